// Round 2
// baseline (1805.857 us; speedup 1.0000x reference)
//
#include <hip/hip_runtime.h>
#include <hip/hip_bf16.h>
#include <stdint.h>

// Problem constants
#define BATCH 4
#define NPTS  8192
#define KNN   24
#define DPT   32     // D_POINTS
#define DM    64     // D_MODEL
#define PED   60     // PE_DIM
#define DK    (DM*KNN)      // 1536
#define ROWS  (BATCH*NPTS)  // 32768

// KNN spatial grid
#define GRIDN 16
#define NCELL (GRIDN*GRIDN*GRIDN)   // 4096
#define CH    0.0625f               // cell width = 1/16 (exact in fp32)

typedef __attribute__((ext_vector_type(8))) short short8;
typedef __attribute__((ext_vector_type(4))) float f32x4;
typedef __attribute__((address_space(3))) unsigned lds_u32;
typedef const __attribute__((address_space(1))) unsigned gbl_u32;

#define WSYNC() __builtin_amdgcn_wave_barrier()

static __device__ __forceinline__ unsigned short f2bf(float f) {
  __hip_bfloat16 h = __float2bfloat16(f);
  return *(unsigned short*)&h;
}

static __device__ __forceinline__ int cell_coord(float p) {
  int c = (int)(p * (float)GRIDN);
  c = (c < 0) ? 0 : c;
  c = (c > GRIDN - 1) ? GRIDN - 1 : c;
  return c;
}

// ---------------------------------------------------------------------------
// K1: x = features @ W1.T + b1     [ROWS,32] x [64,32]^T -> [ROWS,64]
// ---------------------------------------------------------------------------
__global__ __launch_bounds__(256) void fc1_kernel(
    const float* __restrict__ f, const float* __restrict__ W1,
    const float* __restrict__ b1, float* __restrict__ x) {
  int gid = blockIdx.x * 256 + threadIdx.x;
  int n = gid >> 6, c = gid & 63;
  const float* fr = f + (size_t)n * DPT;
  const float* wr = W1 + c * DPT;
  float acc = b1[c];
#pragma unroll
  for (int i = 0; i < DPT; ++i) acc = fmaf(fr[i], wr[i], acc);
  x[(size_t)n * DM + c] = acc;
}

// ---------------------------------------------------------------------------
// K2a: build per-batch uniform grid over [0,1]^3.
// ---------------------------------------------------------------------------
__global__ __launch_bounds__(256) void grid_build_kernel(
    const float* __restrict__ xyz, int* __restrict__ cellStart,
    int* __restrict__ sortedIdx) {
  __shared__ int cnt[NCELL];     // 16 KB
  __shared__ int partial[256];
  int b = blockIdx.x, tid = threadIdx.x;
  const float* P = xyz + (size_t)b * NPTS * 3;

  for (int i = tid; i < NCELL; i += 256) cnt[i] = 0;
  __syncthreads();
  for (int i = tid; i < NPTS; i += 256) {
    int cx = cell_coord(P[3 * i + 0]);
    int cy = cell_coord(P[3 * i + 1]);
    int cz = cell_coord(P[3 * i + 2]);
    atomicAdd(&cnt[(cx << 8) | (cy << 4) | cz], 1);
  }
  __syncthreads();
  int base = tid * 16, s = 0;
#pragma unroll
  for (int j = 0; j < 16; ++j) s += cnt[base + j];
  partial[tid] = s;
  __syncthreads();
  if (tid == 0) {
    int acc = 0;
    for (int i = 0; i < 256; ++i) { int v = partial[i]; partial[i] = acc; acc += v; }
  }
  __syncthreads();
  int acc = partial[tid];
#pragma unroll
  for (int j = 0; j < 16; ++j) {
    int c = cnt[base + j];
    cnt[base + j] = acc;                          // becomes scatter cursor
    cellStart[b * (NCELL + 1) + base + j] = acc;  // exclusive start
    acc += c;
  }
  if (tid == 255) cellStart[b * (NCELL + 1) + NCELL] = NPTS;
  __syncthreads();
  for (int i = tid; i < NPTS; i += 256) {
    int cx = cell_coord(P[3 * i + 0]);
    int cy = cell_coord(P[3 * i + 1]);
    int cz = cell_coord(P[3 * i + 2]);
    int pos = atomicAdd(&cnt[(cx << 8) | (cy << 4) | cz], 1);
    sortedIdx[b * NPTS + pos] = i;
  }
}

// ---------------------------------------------------------------------------
// K2b: exact KNN via expanding cell shells + per-cell ball pruning.
// Distance metric IDENTICAL to the verified full-scan kernel.
// ---------------------------------------------------------------------------
__global__ __launch_bounds__(64) void grid_knn_kernel(
    const float* __restrict__ xyz, const int* __restrict__ cellStart,
    const int* __restrict__ sortedIdx, int* __restrict__ knn) {
  int t = blockIdx.x * 64 + threadIdx.x;   // 0..32767 sorted position
  int b = t >> 13, j = t & 8191;
  const int* cs = cellStart + b * (NCELL + 1);
  const int* si = sortedIdx + b * NPTS;
  const float* P = xyz + (size_t)b * NPTS * 3;

  int q = si[j];                // local point index (query)
  int n = (b << 13) + q;        // global row
  float qx = P[3 * q + 0], qy = P[3 * q + 1], qz = P[3 * q + 2];
  int cx = cell_coord(qx), cy = cell_coord(qy), cz = cell_coord(qz);

  unsigned long long key[KNN];
#pragma unroll
  for (int o = 0; o < KNN; ++o) key[o] = 0x7F800000FFFFFFFFULL;
  float lim = __builtin_inff();

  for (int rho = 0; rho <= GRIDN - 1; ++rho) {
    for (int dz = -rho; dz <= rho; ++dz) {
      int iz = cz + dz;
      if ((unsigned)iz >= GRIDN) continue;
      bool zface = (dz == -rho) || (dz == rho);
      for (int dy = -rho; dy <= rho; ++dy) {
        int iy = cy + dy;
        if ((unsigned)iy >= GRIDN) continue;
        bool face = zface || (dy == -rho) || (dy == rho);
        int dxstep = (rho == 0 || face) ? 1 : (2 * rho);
        for (int dx = -rho; dx <= rho; dx += dxstep) {
          int ix = cx + dx;
          if ((unsigned)ix >= GRIDN) continue;
          float bx = ix * CH, by = iy * CH, bz = iz * CH;
          float ex = fmaxf(fmaxf(bx - qx, qx - (bx + CH)), 0.f);
          float ey = fmaxf(fmaxf(by - qy, qy - (by + CH)), 0.f);
          float ez = fmaxf(fmaxf(bz - qz, qz - (bz + CH)), 0.f);
          float dsq = ex * ex + ey * ey + ez * ez;
          if (dsq * 0.99999f >= lim) continue;   // cannot beat current 24th
          int cid = (ix << 8) | (iy << 4) | iz;
          int s0 = cs[cid], s1 = cs[cid + 1];
          for (int ii = s0; ii < s1; ++ii) {
            int m = si[ii];
            float ddx = qx - P[3 * m + 0];
            float ddy = qy - P[3 * m + 1];
            float ddz = qz - P[3 * m + 2];
            double dd = (double)ddx * (double)ddx + (double)ddy * (double)ddy
                      + (double)ddz * (double)ddz;
            float df = (float)dd;
            if (df < lim) {
              unsigned long long v =
                  ((unsigned long long)__float_as_uint(df) << 32) | (unsigned)m;
#pragma unroll
              for (int tt = 0; tt < KNN; ++tt) {
                bool take = v < key[tt];
                unsigned long long old = key[tt];
                key[tt] = take ? v : key[tt];
                v = take ? old : v;
              }
              lim = __uint_as_float((unsigned)(key[KNN - 1] >> 32));
            }
          }
        }
      }
    }
    float rb = rho * CH;
    if (lim < rb * rb * 0.999999f) break;
  }
#pragma unroll
  for (int o = 0; o < KNN; ++o)
    knn[(size_t)n * KNN + o] = (int)(unsigned)key[o];
}

// ---------------------------------------------------------------------------
__device__ __forceinline__ float pe_elem(int t, float gx, float gy, float gz) {
  const float OM[10] = {1.0f, 0.3981071705534972f, 0.15848931924611134f,
                        0.06309573444801933f, 0.025118864315095794f, 0.01f,
                        0.003981071705534973f, 0.001584893192461114f,
                        0.0006309573444801933f, 0.00025118864315095795f};
  int a = t / 20, r = t % 20;
  float g = (a == 0) ? gx : ((a == 1) ? gy : gz);
  float ang = g * OM[r % 10];
  return (r < 10) ? __sinf(ang) : __cosf(ang);
}

// ---------------------------------------------------------------------------
// K3: pre[n, k*64+c] = q_c - kf_c + pos_enc_c  (f32, into attn region).
// Block 256 = 4 queries, one per wave; Wd1/Wd2 rows in registers; wave-sync.
// 4-way split accumulators break the serial fmaf dependence chain.
// ---------------------------------------------------------------------------
__global__ __launch_bounds__(256) void prebuild_kernel(
    const float* __restrict__ xyz, const float* __restrict__ x,
    const int* __restrict__ knn,
    const float* __restrict__ Wd1, const float* __restrict__ bd1,
    const float* __restrict__ Wd2, const float* __restrict__ bd2,
    float* __restrict__ pre) {
  __shared__ float sPe[4][64];
  __shared__ float sH[4][64];
  __shared__ int   sIdx[4][KNN];
  int tid = threadIdx.x, w = tid >> 6, c = tid & 63;
  int n = blockIdx.x * 4 + w, b = n >> 13;

  float wd1r[PED], wd2r[DM];
#pragma unroll
  for (int j = 0; j < PED; ++j) wd1r[j] = Wd1[c * PED + j];
#pragma unroll
  for (int o = 0; o < DM; ++o) wd2r[o] = Wd2[c * DM + o];

  if (c < KNN) sIdx[w][c] = knn[(size_t)n * KNN + c];
  float qx = xyz[(size_t)n * 3], qy = xyz[(size_t)n * 3 + 1], qz = xyz[(size_t)n * 3 + 2];
  float xq = x[(size_t)n * DM + c];
  float bd1v = bd1[c], bd2v = bd2[c];
  WSYNC();

  for (int k = 0; k < KNN; ++k) {
    int gidx = (b << 13) + sIdx[w][k];
    float gx = qx - xyz[(size_t)gidx * 3];
    float gy = qy - xyz[(size_t)gidx * 3 + 1];
    float gz = qz - xyz[(size_t)gidx * 3 + 2];
    if (c < PED) sPe[w][c] = pe_elem(c, gx, gy, gz);
    WSYNC();
    float h0 = bd1v, h1 = 0.f, h2 = 0.f, h3 = 0.f;
    const float4* p4 = (const float4*)&sPe[w][0];
#pragma unroll
    for (int jj = 0; jj < 15; ++jj) {
      float4 pv = p4[jj];
      h0 = fmaf(pv.x, wd1r[4 * jj + 0], h0);
      h1 = fmaf(pv.y, wd1r[4 * jj + 1], h1);
      h2 = fmaf(pv.z, wd1r[4 * jj + 2], h2);
      h3 = fmaf(pv.w, wd1r[4 * jj + 3], h3);
    }
    sH[w][c] = fmaxf((h0 + h1) + (h2 + h3), 0.f);
    WSYNC();
    float p0 = bd2v, p1 = 0.f, p2 = 0.f, p3 = 0.f;
    const float4* h4 = (const float4*)&sH[w][0];
#pragma unroll
    for (int oo = 0; oo < 16; ++oo) {
      float4 hv = h4[oo];
      p0 = fmaf(hv.x, wd2r[4 * oo + 0], p0);
      p1 = fmaf(hv.y, wd2r[4 * oo + 1], p1);
      p2 = fmaf(hv.z, wd2r[4 * oo + 2], p2);
      p3 = fmaf(hv.w, wd2r[4 * oo + 3], p3);
    }
    float p = (p0 + p1) + (p2 + p3);
    float kfv = x[(size_t)gidx * DM + c];
    pre[((size_t)n * KNN + k) * DM + c] = xq - kfv + p;
    WSYNC();
  }
}

// ---------------------------------------------------------------------------
// K4a: f32 -> bf16 convert (vectorized)
// ---------------------------------------------------------------------------
__global__ __launch_bounds__(256) void conv_bf16_kernel(
    const float* __restrict__ src, unsigned short* __restrict__ dst, int n4) {
  int i = blockIdx.x * 256 + threadIdx.x;
  if (i < n4) {
    float4 v = ((const float4*)src)[i];
    ushort4 o;
    o.x = f2bf(v.x); o.y = f2bf(v.y); o.z = f2bf(v.z); o.w = f2bf(v.w);
    ((ushort4*)dst)[i] = o;
  }
}

// ---------------------------------------------------------------------------
// K4b: logits = pre_bf16 @ Wa_bf16.T + ba  via MFMA 16x16x32, 128x128 tiles.
// ---------------------------------------------------------------------------
__global__ __launch_bounds__(256) void gemm_bf16_kernel(
    const unsigned short* __restrict__ A,   // [cr][1536] bf16
    const unsigned short* __restrict__ B,   // Wa bf16 [1536][1536]
    const float* __restrict__ ba,
    float* __restrict__ C) {                // [cr][1536] f32
  __shared__ unsigned short sA[8 * 512];
  __shared__ unsigned short sB[8 * 512];
  int tid = threadIdx.x, w = tid >> 6, L = tid & 63;
  int m0 = blockIdx.y * 128, n0 = blockIdx.x * 128;
  int wr = w >> 1, wc = w & 1;
  int lrow = L & 15, lq = L >> 4;

  f32x4 acc[4][4];
#pragma unroll
  for (int i = 0; i < 4; ++i)
#pragma unroll
    for (int j = 0; j < 4; ++j) acc[i][j] = (f32x4){0.f, 0.f, 0.f, 0.f};

  for (int kt = 0; kt < DK; kt += 32) {
#pragma unroll
    for (int i = 0; i < 2; ++i) {
      int tb = w * 2 + i;
      const unsigned short* ga = A + ((size_t)(m0 + tb * 16 + lrow)) * DK + kt + lq * 8;
      __builtin_amdgcn_global_load_lds((gbl_u32*)ga, (lds_u32*)(sA + tb * 512), 16, 0, 0);
      const unsigned short* gb = B + ((size_t)(n0 + tb * 16 + lrow)) * DK + kt + lq * 8;
      __builtin_amdgcn_global_load_lds((gbl_u32*)gb, (lds_u32*)(sB + tb * 512), 16, 0, 0);
    }
    __syncthreads();
    short8 af[4], bf[4];
#pragma unroll
    for (int i = 0; i < 4; ++i)
      af[i] = *(const short8*)(sA + ((wr * 4 + i) * 64 + L) * 8);
#pragma unroll
    for (int j = 0; j < 4; ++j)
      bf[j] = *(const short8*)(sB + ((wc * 4 + j) * 64 + L) * 8);
#pragma unroll
    for (int i = 0; i < 4; ++i)
#pragma unroll
      for (int j = 0; j < 4; ++j)
        acc[i][j] = __builtin_amdgcn_mfma_f32_16x16x32_bf16(af[i], bf[j], acc[i][j], 0, 0, 0);
    __syncthreads();
  }
#pragma unroll
  for (int j = 0; j < 4; ++j) {
    int col = n0 + (wc * 4 + j) * 16 + lrow;
    float bav = ba[col];
#pragma unroll
    for (int i = 0; i < 4; ++i) {
      int rbase = m0 + (wr * 4 + i) * 16 + lq * 4;
#pragma unroll
      for (int r = 0; r < 4; ++r)
        C[(size_t)(rbase + r) * DK + col] = acc[i][j][r] + bav;
    }
  }
}

// ---------------------------------------------------------------------------
// K5: softmax over K, recompute pos_enc, einsum, fc2 + residual.
// Block 256 = 4 queries (one per wave), wave-sync k-loop.
// Wd1/Wd2 rows in REGISTERS (prebuild-style); broadcast float4 LDS reads;
// 4-way split accumulators. W2 stays in LDS (used once per query,
// stride-65 rows -> conflict-free).
// ---------------------------------------------------------------------------
__global__ __launch_bounds__(256) void finish_kernel(
    const float* __restrict__ xyz, const float* __restrict__ x,
    const int* __restrict__ knn,
    const float* __restrict__ Wd1, const float* __restrict__ bd1,
    const float* __restrict__ Wd2, const float* __restrict__ bd2,
    const float* __restrict__ W2, const float* __restrict__ b2,
    float* __restrict__ attn, float* __restrict__ res) {
  __shared__ float sW2[DM][DM + 1];   // 16.6 KB
  __shared__ float sPe[4][64];
  __shared__ float sH[4][64];
  __shared__ float sRes[4][64];
  __shared__ int   sIdx[4][KNN];
  int tid = threadIdx.x, w = tid >> 6, c = tid & 63;
  int n = blockIdx.x * 4 + w, b = n >> 13;

  float wd1r[PED], wd2r[DM];
#pragma unroll
  for (int j = 0; j < PED; ++j) wd1r[j] = Wd1[c * PED + j];
#pragma unroll
  for (int o = 0; o < DM; ++o) wd2r[o] = Wd2[c * DM + o];

  for (int q = tid; q < DM * DM; q += 256) sW2[q >> 6][q & 63] = W2[q];
  if (c < KNN) sIdx[w][c] = knn[(size_t)n * KNN + c];
  __syncthreads();

  float L[KNN];
  float mx = -__builtin_inff();
#pragma unroll
  for (int k = 0; k < KNN; ++k) {
    L[k] = attn[((size_t)n * KNN + k) * DM + c];
    mx = fmaxf(mx, L[k]);
  }
  float ssum = 0.f;
#pragma unroll
  for (int k = 0; k < KNN; ++k) { L[k] = __expf((L[k] - mx) * 0.125f); ssum += L[k]; }
  float inv = 1.0f / ssum;
#pragma unroll
  for (int k = 0; k < KNN; ++k) {
    L[k] *= inv;
    attn[((size_t)n * KNN + k) * DM + c] = L[k];
  }

  float qx = xyz[(size_t)n * 3], qy = xyz[(size_t)n * 3 + 1], qz = xyz[(size_t)n * 3 + 2];
  float bd1v = bd1[c], bd2v = bd2[c];
  float racc = 0.f;
  for (int k = 0; k < KNN; ++k) {
    int gidx = (b << 13) + sIdx[w][k];
    float gx = qx - xyz[(size_t)gidx * 3];
    float gy = qy - xyz[(size_t)gidx * 3 + 1];
    float gz = qz - xyz[(size_t)gidx * 3 + 2];
    if (c < PED) sPe[w][c] = pe_elem(c, gx, gy, gz);
    WSYNC();
    float h0 = bd1v, h1 = 0.f, h2 = 0.f, h3 = 0.f;
    const float4* p4 = (const float4*)&sPe[w][0];
#pragma unroll
    for (int jj = 0; jj < 15; ++jj) {
      float4 pv = p4[jj];
      h0 = fmaf(pv.x, wd1r[4 * jj + 0], h0);
      h1 = fmaf(pv.y, wd1r[4 * jj + 1], h1);
      h2 = fmaf(pv.z, wd1r[4 * jj + 2], h2);
      h3 = fmaf(pv.w, wd1r[4 * jj + 3], h3);
    }
    sH[w][c] = fmaxf((h0 + h1) + (h2 + h3), 0.f);
    WSYNC();
    float p0 = bd2v, p1 = 0.f, p2 = 0.f, p3 = 0.f;
    const float4* h4 = (const float4*)&sH[w][0];
#pragma unroll
    for (int oo = 0; oo < 16; ++oo) {
      float4 hv = h4[oo];
      p0 = fmaf(hv.x, wd2r[4 * oo + 0], p0);
      p1 = fmaf(hv.y, wd2r[4 * oo + 1], p1);
      p2 = fmaf(hv.z, wd2r[4 * oo + 2], p2);
      p3 = fmaf(hv.w, wd2r[4 * oo + 3], p3);
    }
    float p = (p0 + p1) + (p2 + p3);
    racc = fmaf(L[k], x[(size_t)gidx * DM + c] + p, racc);
    WSYNC();
  }
  sRes[w][c] = racc;
  WSYNC();
  float oacc = b2[c] + x[(size_t)n * DM + c];
#pragma unroll
  for (int o = 0; o < DM; ++o) oacc = fmaf(sRes[w][o], sW2[c][o], oacc);
  res[(size_t)n * DM + c] = oacc;
}

// ---------------------------------------------------------------------------
extern "C" void kernel_launch(void* const* d_in, const int* in_sizes, int n_in,
                              void* d_out, int out_size, void* d_ws, size_t ws_size,
                              hipStream_t stream) {
  const float* features = (const float*)d_in[0];
  const float* xyz = (const float*)d_in[1];
  const float* W1  = (const float*)d_in[2];
  const float* b1  = (const float*)d_in[3];
  const float* W2  = (const float*)d_in[4];
  const float* b2  = (const float*)d_in[5];
  const float* Wd1 = (const float*)d_in[6];
  const float* bd1 = (const float*)d_in[7];
  const float* Wd2 = (const float*)d_in[8];
  const float* bd2 = (const float*)d_in[9];
  const float* Wa  = (const float*)d_in[10];
  const float* ba  = (const float*)d_in[11];

  float* res  = (float*)d_out;                      // [ROWS*64]
  float* attn = (float*)d_out + (size_t)ROWS * DM;  // [ROWS*1536] pre/logits/attn

  size_t xB   = (size_t)ROWS * DM * 4;              // 8,388,608
  size_t knnB = (size_t)ROWS * KNN * 4;             // 3,145,728
  size_t WaB  = (size_t)DK * DK * 2;                // 4,718,592
  size_t used = xB + knnB;                          // proven ws >= ~12 MB (round 1)
  float* xbuf = (float*)d_ws;
  int*   knn  = (int*)((char*)d_ws + xB);

  unsigned short *WaBf, *chunk;
  int chunk_rows;
  size_t avail = (ws_size > used) ? ws_size - used : 0;
  size_t rowB = (size_t)DK * 2;
  if (avail >= WaB + 128 * rowB) {                  // scratch fits in ws
    WaBf  = (unsigned short*)((char*)d_ws + used);
    chunk = (unsigned short*)((char*)d_ws + used + WaB);
    size_t cr = (avail - WaB) / rowB;
    chunk_rows = (cr > ROWS) ? ROWS : (int)cr;
    chunk_rows &= ~127;
  } else {                                          // fallback: res region scratch
    WaBf  = (unsigned short*)d_out;
    chunk = (unsigned short*)((char*)d_out + WaB);
    chunk_rows = (int)((xB - WaB) / rowB) & ~127;   // 1152
  }

  // Grid scratch lives at the head of the attn region: it is fully consumed
  // by grid_knn before prebuild first writes to attn (stream-ordered).
  int* gridCS = (int*)attn;                         // [BATCH][NCELL+1]
  int* gridSI = gridCS + BATCH * (NCELL + 1);       // [BATCH][NPTS]

  hipLaunchKernelGGL(fc1_kernel, dim3(ROWS * DM / 256), dim3(256), 0, stream,
                     features, W1, b1, xbuf);
  hipLaunchKernelGGL(grid_build_kernel, dim3(BATCH), dim3(256), 0, stream,
                     xyz, gridCS, gridSI);
  hipLaunchKernelGGL(grid_knn_kernel, dim3(ROWS / 64), dim3(64), 0, stream,
                     xyz, gridCS, gridSI, knn);
  hipLaunchKernelGGL(prebuild_kernel, dim3(ROWS / 4), dim3(256), 0, stream,
                     xyz, xbuf, knn, Wd1, bd1, Wd2, bd2, attn);
  {
    int n4 = DK * DK / 4;
    hipLaunchKernelGGL(conv_bf16_kernel, dim3((n4 + 255) / 256), dim3(256), 0, stream,
                       Wa, WaBf, n4);
  }
  for (int r0 = 0; r0 < ROWS; r0 += chunk_rows) {
    int cr = (ROWS - r0 < chunk_rows) ? (ROWS - r0) : chunk_rows;
    int n4 = cr * DK / 4;
    hipLaunchKernelGGL(conv_bf16_kernel, dim3((n4 + 255) / 256), dim3(256), 0, stream,
                       attn + (size_t)r0 * DK, chunk, n4);
    hipLaunchKernelGGL(gemm_bf16_kernel, dim3(DK / 128, cr / 128), dim3(256), 0, stream,
                       chunk, WaBf, ba, attn + (size_t)r0 * DK);
  }
  hipLaunchKernelGGL(finish_kernel, dim3(ROWS / 4), dim3(256), 0, stream,
                     xyz, xbuf, knn, Wd1, bd1, Wd2, bd2, W2, b2, attn, res);
}

// Round 3
// 1173.222 us; speedup vs baseline: 1.5392x; 1.5392x over previous
//
#include <hip/hip_runtime.h>
#include <hip/hip_bf16.h>
#include <stdint.h>

// Problem constants
#define BATCH 4
#define NPTS  8192
#define KNN   24
#define DPT   32     // D_POINTS
#define DM    64     // D_MODEL
#define PED   60     // PE_DIM
#define DK    (DM*KNN)      // 1536
#define ROWS  (BATCH*NPTS)  // 32768

// KNN spatial grid
#define GRIDN 16
#define NCELL (GRIDN*GRIDN*GRIDN)   // 4096
#define CH    0.0625f               // cell width = 1/16 (exact in fp32)

typedef __attribute__((ext_vector_type(8))) short short8;
typedef __attribute__((ext_vector_type(4))) float f32x4;
typedef __attribute__((address_space(3))) unsigned lds_u32;
typedef const __attribute__((address_space(1))) unsigned gbl_u32;

#define WSYNC() __builtin_amdgcn_wave_barrier()

static __device__ __forceinline__ unsigned short f2bf(float f) {
  __hip_bfloat16 h = __float2bfloat16(f);
  return *(unsigned short*)&h;
}
static __device__ __forceinline__ float bf2f(unsigned short u) {
  return __uint_as_float(((unsigned)u) << 16);
}

static __device__ __forceinline__ int cell_coord(float p) {
  int c = (int)(p * (float)GRIDN);
  c = (c < 0) ? 0 : c;
  c = (c > GRIDN - 1) ? GRIDN - 1 : c;
  return c;
}

// ---------------------------------------------------------------------------
// K1: x = features @ W1.T + b1     [ROWS,32] x [64,32]^T -> [ROWS,64]
// ---------------------------------------------------------------------------
__global__ __launch_bounds__(256) void fc1_kernel(
    const float* __restrict__ f, const float* __restrict__ W1,
    const float* __restrict__ b1, float* __restrict__ x) {
  int gid = blockIdx.x * 256 + threadIdx.x;
  int n = gid >> 6, c = gid & 63;
  const float* fr = f + (size_t)n * DPT;
  const float* wr = W1 + c * DPT;
  float acc = b1[c];
#pragma unroll
  for (int i = 0; i < DPT; ++i) acc = fmaf(fr[i], wr[i], acc);
  x[(size_t)n * DM + c] = acc;
}

// ---------------------------------------------------------------------------
// K2a: build per-batch uniform grid over [0,1]^3.
// ---------------------------------------------------------------------------
__global__ __launch_bounds__(256) void grid_build_kernel(
    const float* __restrict__ xyz, int* __restrict__ cellStart,
    int* __restrict__ sortedIdx) {
  __shared__ int cnt[NCELL];     // 16 KB
  __shared__ int partial[256];
  int b = blockIdx.x, tid = threadIdx.x;
  const float* P = xyz + (size_t)b * NPTS * 3;

  for (int i = tid; i < NCELL; i += 256) cnt[i] = 0;
  __syncthreads();
  for (int i = tid; i < NPTS; i += 256) {
    int cx = cell_coord(P[3 * i + 0]);
    int cy = cell_coord(P[3 * i + 1]);
    int cz = cell_coord(P[3 * i + 2]);
    atomicAdd(&cnt[(cx << 8) | (cy << 4) | cz], 1);
  }
  __syncthreads();
  int base = tid * 16, s = 0;
#pragma unroll
  for (int j = 0; j < 16; ++j) s += cnt[base + j];
  partial[tid] = s;
  __syncthreads();
  if (tid == 0) {
    int acc = 0;
    for (int i = 0; i < 256; ++i) { int v = partial[i]; partial[i] = acc; acc += v; }
  }
  __syncthreads();
  int acc = partial[tid];
#pragma unroll
  for (int j = 0; j < 16; ++j) {
    int c = cnt[base + j];
    cnt[base + j] = acc;                          // becomes scatter cursor
    cellStart[b * (NCELL + 1) + base + j] = acc;  // exclusive start
    acc += c;
  }
  if (tid == 255) cellStart[b * (NCELL + 1) + NCELL] = NPTS;
  __syncthreads();
  for (int i = tid; i < NPTS; i += 256) {
    int cx = cell_coord(P[3 * i + 0]);
    int cy = cell_coord(P[3 * i + 1]);
    int cz = cell_coord(P[3 * i + 2]);
    int pos = atomicAdd(&cnt[(cx << 8) | (cy << 4) | cz], 1);
    sortedIdx[b * NPTS + pos] = i;
  }
}

// ---------------------------------------------------------------------------
// K2b: exact KNN via expanding cell shells + per-cell ball pruning.
// Distance metric IDENTICAL to the verified full-scan kernel.
// ---------------------------------------------------------------------------
__global__ __launch_bounds__(64) void grid_knn_kernel(
    const float* __restrict__ xyz, const int* __restrict__ cellStart,
    const int* __restrict__ sortedIdx, int* __restrict__ knn) {
  int t = blockIdx.x * 64 + threadIdx.x;   // 0..32767 sorted position
  int b = t >> 13, j = t & 8191;
  const int* cs = cellStart + b * (NCELL + 1);
  const int* si = sortedIdx + b * NPTS;
  const float* P = xyz + (size_t)b * NPTS * 3;

  int q = si[j];                // local point index (query)
  int n = (b << 13) + q;        // global row
  float qx = P[3 * q + 0], qy = P[3 * q + 1], qz = P[3 * q + 2];
  int cx = cell_coord(qx), cy = cell_coord(qy), cz = cell_coord(qz);

  unsigned long long key[KNN];
#pragma unroll
  for (int o = 0; o < KNN; ++o) key[o] = 0x7F800000FFFFFFFFULL;
  float lim = __builtin_inff();

  for (int rho = 0; rho <= GRIDN - 1; ++rho) {
    for (int dz = -rho; dz <= rho; ++dz) {
      int iz = cz + dz;
      if ((unsigned)iz >= GRIDN) continue;
      bool zface = (dz == -rho) || (dz == rho);
      for (int dy = -rho; dy <= rho; ++dy) {
        int iy = cy + dy;
        if ((unsigned)iy >= GRIDN) continue;
        bool face = zface || (dy == -rho) || (dy == rho);
        int dxstep = (rho == 0 || face) ? 1 : (2 * rho);
        for (int dx = -rho; dx <= rho; dx += dxstep) {
          int ix = cx + dx;
          if ((unsigned)ix >= GRIDN) continue;
          float bx = ix * CH, by = iy * CH, bz = iz * CH;
          float ex = fmaxf(fmaxf(bx - qx, qx - (bx + CH)), 0.f);
          float ey = fmaxf(fmaxf(by - qy, qy - (by + CH)), 0.f);
          float ez = fmaxf(fmaxf(bz - qz, qz - (bz + CH)), 0.f);
          float dsq = ex * ex + ey * ey + ez * ez;
          if (dsq * 0.99999f >= lim) continue;   // cannot beat current 24th
          int cid = (ix << 8) | (iy << 4) | iz;
          int s0 = cs[cid], s1 = cs[cid + 1];
          for (int ii = s0; ii < s1; ++ii) {
            int m = si[ii];
            float ddx = qx - P[3 * m + 0];
            float ddy = qy - P[3 * m + 1];
            float ddz = qz - P[3 * m + 2];
            double dd = (double)ddx * (double)ddx + (double)ddy * (double)ddy
                      + (double)ddz * (double)ddz;
            float df = (float)dd;
            if (df < lim) {
              unsigned long long v =
                  ((unsigned long long)__float_as_uint(df) << 32) | (unsigned)m;
#pragma unroll
              for (int tt = 0; tt < KNN; ++tt) {
                bool take = v < key[tt];
                unsigned long long old = key[tt];
                key[tt] = take ? v : key[tt];
                v = take ? old : v;
              }
              lim = __uint_as_float((unsigned)(key[KNN - 1] >> 32));
            }
          }
        }
      }
    }
    float rb = rho * CH;
    if (lim < rb * rb * 0.999999f) break;
  }
#pragma unroll
  for (int o = 0; o < KNN; ++o)
    knn[(size_t)n * KNN + o] = (int)(unsigned)key[o];
}

// ---------------------------------------------------------------------------
__device__ __forceinline__ float pe_elem(int t, float gx, float gy, float gz) {
  const float OM[10] = {1.0f, 0.3981071705534972f, 0.15848931924611134f,
                        0.06309573444801933f, 0.025118864315095794f, 0.01f,
                        0.003981071705534973f, 0.001584893192461114f,
                        0.0006309573444801933f, 0.00025118864315095795f};
  int a = t / 20, r = t % 20;
  float g = (a == 0) ? gx : ((a == 1) ? gy : gz);
  float ang = g * OM[r % 10];
  return (r < 10) ? __sinf(ang) : __cosf(ang);
}

// ---------------------------------------------------------------------------
// Shared MFMA MLP machinery (per-wave, one query per wave).
// sScr per-wave scratch (2176 ushorts): first holds PE bf16 [32][64]
// (XOR-swizzled), then H bf16 [32][64] (swizzled), then P bf16 [32][68]
// (unswizzled).  Fragment layouts mirror the verified gemm kernel:
//   A/B frag: lane holds row (ln&15), k-span (ln>>4)*8..+8  (short8)
//   C/D:      lane holds col (ln&15), rows (ln>>4)*4+r
// ---------------------------------------------------------------------------
static __device__ __forceinline__ void pe_fill(
    unsigned short* scr, const float* __restrict__ xyz, const int* idxArr,
    int base, float qx, float qy, float qz, int ln) {
  for (int k = 0; k < KNN; ++k) {
    int gidx = base + idxArr[k];
    float gx = qx - xyz[(size_t)gidx * 3 + 0];
    float gy = qy - xyz[(size_t)gidx * 3 + 1];
    float gz = qz - xyz[(size_t)gidx * 3 + 2];
    float v = (ln < PED) ? pe_elem(ln, gx, gy, gz) : 0.f;
    scr[(k * 64 + ln) ^ ((k & 7) << 3)] = f2bf(v);
  }
#pragma unroll
  for (int k = KNN; k < 32; ++k)
    scr[(k * 64 + ln) ^ ((k & 7) << 3)] = 0;
  WSYNC();
}

static __device__ __forceinline__ short8 lds_read8(const unsigned short* p) {
  return *(const short8*)p;
}

static __device__ __forceinline__ void mlp_wave(
    unsigned short* scr, const unsigned short* w1b, const unsigned short* w2b,
    const float* __restrict__ bd1, const float* __restrict__ bd2, int ln) {
  int lrow = ln & 15, lq = ln >> 4;
  short8 af[2][2], bfr[4][2];
  f32x4 acc[2][4];

  // ---- layer 1: H = relu(PE @ Wd1^T + bd1)
#pragma unroll
  for (int mt = 0; mt < 2; ++mt)
#pragma unroll
    for (int ks = 0; ks < 2; ++ks) {
      int row = mt * 16 + lrow;
      af[mt][ks] = lds_read8(scr + ((row * 64 + ks * 32 + lq * 8) ^ ((row & 7) << 3)));
    }
#pragma unroll
  for (int nt = 0; nt < 4; ++nt)
#pragma unroll
    for (int ks = 0; ks < 2; ++ks) {
      int row = nt * 16 + lrow;
      bfr[nt][ks] = lds_read8(w1b + ((row * 64 + ks * 32 + lq * 8) ^ ((row & 7) << 3)));
    }
#pragma unroll
  for (int mt = 0; mt < 2; ++mt)
#pragma unroll
    for (int nt = 0; nt < 4; ++nt) {
      f32x4 a = (f32x4){0.f, 0.f, 0.f, 0.f};
      a = __builtin_amdgcn_mfma_f32_16x16x32_bf16(af[mt][0], bfr[nt][0], a, 0, 0, 0);
      a = __builtin_amdgcn_mfma_f32_16x16x32_bf16(af[mt][1], bfr[nt][1], a, 0, 0, 0);
      acc[mt][nt] = a;
    }
  WSYNC();
  // write H bf16 swizzled [32][64] (overwrites PE region; frag reads done)
#pragma unroll
  for (int mt = 0; mt < 2; ++mt)
#pragma unroll
    for (int nt = 0; nt < 4; ++nt) {
      float b1v = bd1[nt * 16 + lrow];
#pragma unroll
      for (int r = 0; r < 4; ++r) {
        int row = mt * 16 + lq * 4 + r;
        int col = nt * 16 + lrow;
        scr[(row * 64 + col) ^ ((row & 7) << 3)] =
            f2bf(fmaxf(acc[mt][nt][r] + b1v, 0.f));
      }
    }
  WSYNC();
  // ---- layer 2: P = H @ Wd2^T + bd2
#pragma unroll
  for (int mt = 0; mt < 2; ++mt)
#pragma unroll
    for (int ks = 0; ks < 2; ++ks) {
      int row = mt * 16 + lrow;
      af[mt][ks] = lds_read8(scr + ((row * 64 + ks * 32 + lq * 8) ^ ((row & 7) << 3)));
    }
#pragma unroll
  for (int nt = 0; nt < 4; ++nt)
#pragma unroll
    for (int ks = 0; ks < 2; ++ks) {
      int row = nt * 16 + lrow;
      bfr[nt][ks] = lds_read8(w2b + ((row * 64 + ks * 32 + lq * 8) ^ ((row & 7) << 3)));
    }
#pragma unroll
  for (int mt = 0; mt < 2; ++mt)
#pragma unroll
    for (int nt = 0; nt < 4; ++nt) {
      f32x4 a = (f32x4){0.f, 0.f, 0.f, 0.f};
      a = __builtin_amdgcn_mfma_f32_16x16x32_bf16(af[mt][0], bfr[nt][0], a, 0, 0, 0);
      a = __builtin_amdgcn_mfma_f32_16x16x32_bf16(af[mt][1], bfr[nt][1], a, 0, 0, 0);
      acc[mt][nt] = a;
    }
  WSYNC();
  // write P bf16 [32][68] unswizzled (overwrites H region; frag reads done)
#pragma unroll
  for (int mt = 0; mt < 2; ++mt)
#pragma unroll
    for (int nt = 0; nt < 4; ++nt) {
      float b2v = bd2[nt * 16 + lrow];
#pragma unroll
      for (int r = 0; r < 4; ++r) {
        int row = mt * 16 + lq * 4 + r;
        int col = nt * 16 + lrow;
        scr[row * 68 + col] = f2bf(acc[mt][nt][r] + b2v);
      }
    }
  WSYNC();
}

// ---------------------------------------------------------------------------
// K3: pre16[n, k*64+c] = bf16(q_c - kf_c + pos_enc_c)  (bf16, attn front).
// Block 256 = 4 queries (one per wave); MLP via MFMA.
// ---------------------------------------------------------------------------
__global__ __launch_bounds__(256) void prebuild_kernel(
    const float* __restrict__ xyz, const float* __restrict__ x,
    const int* __restrict__ knn,
    const float* __restrict__ Wd1, const float* __restrict__ bd1,
    const float* __restrict__ Wd2, const float* __restrict__ bd2,
    unsigned short* __restrict__ pre16) {
  __shared__ unsigned short sW1b[4096];
  __shared__ unsigned short sW2bb[4096];
  __shared__ unsigned short sScr[4][2176];
  __shared__ int sIdx[4][KNN];
  int tid = threadIdx.x, w = tid >> 6, ln = tid & 63;
  int n = blockIdx.x * 4 + w, b = n >> 13;

  for (int q = tid; q < 4096; q += 256) {
    int row = q >> 6, kk = q & 63;
    int idx = q ^ ((row & 7) << 3);
    sW1b[idx] = (kk < PED) ? f2bf(Wd1[row * PED + kk]) : (unsigned short)0;
    sW2bb[idx] = f2bf(Wd2[q]);
  }
  if (ln < KNN) sIdx[w][ln] = knn[(size_t)n * KNN + ln];
  __syncthreads();

  float qx = xyz[(size_t)n * 3], qy = xyz[(size_t)n * 3 + 1], qz = xyz[(size_t)n * 3 + 2];
  float xq = x[(size_t)n * DM + ln];
  unsigned short* scr = &sScr[w][0];

  pe_fill(scr, xyz, &sIdx[w][0], b << 13, qx, qy, qz, ln);
  mlp_wave(scr, sW1b, sW2bb, bd1, bd2, ln);

  for (int k = 0; k < KNN; ++k) {
    int gidx = (b << 13) + sIdx[w][k];
    float kfv = x[(size_t)gidx * DM + ln];
    float p = bf2f(scr[k * 68 + ln]);
    pre16[((size_t)n * KNN + k) * DM + ln] = f2bf(xq - kfv + p);
  }
}

// ---------------------------------------------------------------------------
// K4a: f32 -> bf16 convert (vectorized) — used for Wa only now.
// ---------------------------------------------------------------------------
__global__ __launch_bounds__(256) void conv_bf16_kernel(
    const float* __restrict__ src, unsigned short* __restrict__ dst, int n4) {
  int i = blockIdx.x * 256 + threadIdx.x;
  if (i < n4) {
    float4 v = ((const float4*)src)[i];
    ushort4 o;
    o.x = f2bf(v.x); o.y = f2bf(v.y); o.z = f2bf(v.z); o.w = f2bf(v.w);
    ((ushort4*)dst)[i] = o;
  }
}

// 16B copy kernel (chunk-0 pre rows -> scratch)
__global__ __launch_bounds__(256) void copy16_kernel(
    const uint4* __restrict__ src, uint4* __restrict__ dst, int nvec) {
  int i = blockIdx.x * 256 + threadIdx.x;
  if (i < nvec) dst[i] = src[i];
}

// ---------------------------------------------------------------------------
// K4b: logits = pre_bf16 @ Wa_bf16.T + ba  via MFMA 16x16x32, 128x128 tiles.
// ---------------------------------------------------------------------------
__global__ __launch_bounds__(256) void gemm_bf16_kernel(
    const unsigned short* __restrict__ A,   // [cr][1536] bf16
    const unsigned short* __restrict__ B,   // Wa bf16 [1536][1536]
    const float* __restrict__ ba,
    float* __restrict__ C) {                // [cr][1536] f32
  __shared__ unsigned short sA[8 * 512];
  __shared__ unsigned short sB[8 * 512];
  int tid = threadIdx.x, w = tid >> 6, L = tid & 63;
  int m0 = blockIdx.y * 128, n0 = blockIdx.x * 128;
  int wr = w >> 1, wc = w & 1;
  int lrow = L & 15, lq = L >> 4;

  f32x4 acc[4][4];
#pragma unroll
  for (int i = 0; i < 4; ++i)
#pragma unroll
    for (int j = 0; j < 4; ++j) acc[i][j] = (f32x4){0.f, 0.f, 0.f, 0.f};

  for (int kt = 0; kt < DK; kt += 32) {
#pragma unroll
    for (int i = 0; i < 2; ++i) {
      int tb = w * 2 + i;
      const unsigned short* ga = A + ((size_t)(m0 + tb * 16 + lrow)) * DK + kt + lq * 8;
      __builtin_amdgcn_global_load_lds((gbl_u32*)ga, (lds_u32*)(sA + tb * 512), 16, 0, 0);
      const unsigned short* gb = B + ((size_t)(n0 + tb * 16 + lrow)) * DK + kt + lq * 8;
      __builtin_amdgcn_global_load_lds((gbl_u32*)gb, (lds_u32*)(sB + tb * 512), 16, 0, 0);
    }
    __syncthreads();
    short8 af[4], bf[4];
#pragma unroll
    for (int i = 0; i < 4; ++i)
      af[i] = *(const short8*)(sA + ((wr * 4 + i) * 64 + L) * 8);
#pragma unroll
    for (int j = 0; j < 4; ++j)
      bf[j] = *(const short8*)(sB + ((wc * 4 + j) * 64 + L) * 8);
#pragma unroll
    for (int i = 0; i < 4; ++i)
#pragma unroll
      for (int j = 0; j < 4; ++j)
        acc[i][j] = __builtin_amdgcn_mfma_f32_16x16x32_bf16(af[i], bf[j], acc[i][j], 0, 0, 0);
    __syncthreads();
  }
#pragma unroll
  for (int j = 0; j < 4; ++j) {
    int col = n0 + (wc * 4 + j) * 16 + lrow;
    float bav = ba[col];
#pragma unroll
    for (int i = 0; i < 4; ++i) {
      int rbase = m0 + (wr * 4 + i) * 16 + lq * 4;
#pragma unroll
      for (int r = 0; r < 4; ++r)
        C[(size_t)(rbase + r) * DK + col] = acc[i][j][r] + bav;
    }
  }
}

// ---------------------------------------------------------------------------
// K5: softmax over K, MFMA pos_enc, einsum, fc2 + residual.
// Block 256 = 4 queries (one per wave).
// ---------------------------------------------------------------------------
__global__ __launch_bounds__(256) void finish_kernel(
    const float* __restrict__ xyz, const float* __restrict__ x,
    const int* __restrict__ knn,
    const float* __restrict__ Wd1, const float* __restrict__ bd1,
    const float* __restrict__ Wd2, const float* __restrict__ bd2,
    const float* __restrict__ W2, const float* __restrict__ b2,
    float* __restrict__ attn, float* __restrict__ res) {
  __shared__ unsigned short sW1b[4096];
  __shared__ unsigned short sW2bb[4096];
  __shared__ float sW2f[DM][DM + 1];
  __shared__ unsigned short sScr[4][2176];
  __shared__ float sRes[4][64];
  __shared__ int sIdx[4][KNN];
  int tid = threadIdx.x, w = tid >> 6, ln = tid & 63;
  int n = blockIdx.x * 4 + w, b = n >> 13;

  for (int q = tid; q < 4096; q += 256) {
    int row = q >> 6, kk = q & 63;
    int idx = q ^ ((row & 7) << 3);
    sW1b[idx] = (kk < PED) ? f2bf(Wd1[row * PED + kk]) : (unsigned short)0;
    sW2bb[idx] = f2bf(Wd2[q]);
  }
  for (int q = tid; q < DM * DM; q += 256) sW2f[q >> 6][q & 63] = W2[q];
  if (ln < KNN) sIdx[w][ln] = knn[(size_t)n * KNN + ln];
  __syncthreads();

  float qx = xyz[(size_t)n * 3], qy = xyz[(size_t)n * 3 + 1], qz = xyz[(size_t)n * 3 + 2];
  unsigned short* scr = &sScr[w][0];

  // pos_enc via MFMA (P bf16 lands in scr[k*68+ln])
  pe_fill(scr, xyz, &sIdx[w][0], b << 13, qx, qy, qz, ln);
  mlp_wave(scr, sW1b, sW2bb, bd1, bd2, ln);

  // softmax over k (lane = channel c); coalesced 256B row reads
  float L[KNN];
  float mx = -__builtin_inff();
#pragma unroll
  for (int k = 0; k < KNN; ++k) {
    L[k] = attn[((size_t)n * KNN + k) * DM + ln];
    mx = fmaxf(mx, L[k]);
  }
  float ssum = 0.f;
#pragma unroll
  for (int k = 0; k < KNN; ++k) { L[k] = __expf((L[k] - mx) * 0.125f); ssum += L[k]; }
  float inv = 1.0f / ssum;
#pragma unroll
  for (int k = 0; k < KNN; ++k) {
    L[k] *= inv;
    attn[((size_t)n * KNN + k) * DM + ln] = L[k];
  }

  // einsum: res_c = sum_k L[k] * (x[gidx_k][c] + P[k][c])
  float racc = 0.f;
  for (int k = 0; k < KNN; ++k) {
    int gidx = (b << 13) + sIdx[w][k];
    float xv = x[(size_t)gidx * DM + ln];
    racc = fmaf(L[k], xv + bf2f(scr[k * 68 + ln]), racc);
  }
  sRes[w][ln] = racc;
  WSYNC();
  float oacc = b2[ln] + x[(size_t)n * DM + ln];
#pragma unroll
  for (int o = 0; o < DM; ++o) oacc = fmaf(sRes[w][o], sW2f[ln][o], oacc);
  res[(size_t)n * DM + ln] = oacc;
}

// ---------------------------------------------------------------------------
extern "C" void kernel_launch(void* const* d_in, const int* in_sizes, int n_in,
                              void* d_out, int out_size, void* d_ws, size_t ws_size,
                              hipStream_t stream) {
  const float* features = (const float*)d_in[0];
  const float* xyz = (const float*)d_in[1];
  const float* W1  = (const float*)d_in[2];
  const float* b1  = (const float*)d_in[3];
  const float* W2  = (const float*)d_in[4];
  const float* b2  = (const float*)d_in[5];
  const float* Wd1 = (const float*)d_in[6];
  const float* bd1 = (const float*)d_in[7];
  const float* Wd2 = (const float*)d_in[8];
  const float* bd2 = (const float*)d_in[9];
  const float* Wa  = (const float*)d_in[10];
  const float* ba  = (const float*)d_in[11];

  float* res  = (float*)d_out;                      // [ROWS*64]
  float* attn = (float*)d_out + (size_t)ROWS * DM;  // [ROWS*1536] pre/logits/attn

  size_t xB   = (size_t)ROWS * DM * 4;              // 8,388,608
  size_t knnB = (size_t)ROWS * KNN * 4;             // 3,145,728
  size_t WaB  = (size_t)DK * DK * 2;                // 4,718,592
  size_t used = xB + knnB;
  float* xbuf = (float*)d_ws;
  int*   knn  = (int*)((char*)d_ws + xB);

  unsigned short *WaBf, *chunk;
  int chunk_rows;
  size_t avail = (ws_size > used) ? ws_size - used : 0;
  size_t rowB = (size_t)DK * 2;                     // bf16 row = 3072 B
  if (avail >= WaB + 128 * rowB) {                  // scratch fits in ws
    WaBf  = (unsigned short*)((char*)d_ws + used);
    chunk = (unsigned short*)((char*)d_ws + used + WaB);
    size_t cr = (avail - WaB) / rowB;
    chunk_rows = (cr > ROWS) ? ROWS : (int)cr;
    chunk_rows &= ~127;
  } else {                                          // fallback: res region scratch
    WaBf  = (unsigned short*)d_out;
    chunk = (unsigned short*)((char*)d_out + WaB);
    chunk_rows = (int)((xB - WaB) / rowB) & ~127;   // 1152
  }

  // Grid scratch at the head of the attn region; consumed by grid_knn
  // before prebuild first writes there (stream-ordered).
  int* gridCS = (int*)attn;                         // [BATCH][NCELL+1]
  int* gridSI = gridCS + BATCH * (NCELL + 1);       // [BATCH][NPTS]

  // bf16 pre lives at the FRONT of the attn region (row r at byte r*3072).
  unsigned short* pre16 = (unsigned short*)attn;

  hipLaunchKernelGGL(fc1_kernel, dim3(ROWS * DM / 256), dim3(256), 0, stream,
                     features, W1, b1, xbuf);
  hipLaunchKernelGGL(grid_build_kernel, dim3(BATCH), dim3(256), 0, stream,
                     xyz, gridCS, gridSI);
  hipLaunchKernelGGL(grid_knn_kernel, dim3(ROWS / 64), dim3(64), 0, stream,
                     xyz, gridCS, gridSI, knn);
  hipLaunchKernelGGL(prebuild_kernel, dim3(ROWS / 4), dim3(256), 0, stream,
                     xyz, xbuf, knn, Wd1, bd1, Wd2, bd2, pre16);
  {
    int n4 = DK * DK / 4;
    hipLaunchKernelGGL(conv_bf16_kernel, dim3((n4 + 255) / 256), dim3(256), 0, stream,
                       Wa, WaBf, n4);
  }
  // Copy chunk-0 pre rows to scratch (its in-place slot is clobbered by its
  // own logits writes; every other chunk satisfies cr <= r0 -> safe in place).
  {
    int cr0 = (chunk_rows < ROWS) ? chunk_rows : ROWS;
    int nvec = cr0 * (DK * 2 / 16);                 // cr0 * 192 uint4
    hipLaunchKernelGGL(copy16_kernel, dim3((nvec + 255) / 256), dim3(256), 0, stream,
                       (const uint4*)pre16, (uint4*)chunk, nvec);
  }
  // Descending chunk order: logits row r (byte r*6144) only clobbers pre rows
  // >= 2*r0, which later (lower) chunks never read.
  {
    int top = ((ROWS - 1) / chunk_rows) * chunk_rows;
    for (int r0 = top; r0 >= 0; r0 -= chunk_rows) {
      int cr = (ROWS - r0 < chunk_rows) ? (ROWS - r0) : chunk_rows;
      const unsigned short* Aptr =
          (r0 == 0) ? chunk : pre16 + (size_t)r0 * DK;
      hipLaunchKernelGGL(gemm_bf16_kernel, dim3(DK / 128, cr / 128), dim3(256), 0, stream,
                         Aptr, WaBf, ba, attn + (size_t)r0 * DK);
    }
  }
  hipLaunchKernelGGL(finish_kernel, dim3(ROWS / 4), dim3(256), 0, stream,
                     xyz, xbuf, knn, Wd1, bd1, Wd2, bd2, W2, b2, attn, res);
}

// Round 4
// 1047.789 us; speedup vs baseline: 1.7235x; 1.1197x over previous
//
#include <hip/hip_runtime.h>
#include <hip/hip_bf16.h>
#include <stdint.h>

// Problem constants
#define BATCH 4
#define NPTS  8192
#define KNN   24
#define DPT   32     // D_POINTS
#define DM    64     // D_MODEL
#define PED   60     // PE_DIM
#define DK    (DM*KNN)      // 1536
#define ROWS  (BATCH*NPTS)  // 32768

// KNN spatial grid
#define GRIDN 16
#define NCELL (GRIDN*GRIDN*GRIDN)   // 4096
#define CH    0.0625f               // cell width = 1/16 (exact in fp32)

typedef __attribute__((ext_vector_type(8))) short short8;
typedef __attribute__((ext_vector_type(4))) float f32x4;
typedef __attribute__((address_space(3))) unsigned lds_u32;
typedef const __attribute__((address_space(1))) unsigned gbl_u32;

#define WSYNC() __builtin_amdgcn_wave_barrier()

static __device__ __forceinline__ unsigned short f2bf(float f) {
  __hip_bfloat16 h = __float2bfloat16(f);
  return *(unsigned short*)&h;
}
static __device__ __forceinline__ float bf2f(unsigned short u) {
  return __uint_as_float(((unsigned)u) << 16);
}

static __device__ __forceinline__ int cell_coord(float p) {
  int c = (int)(p * (float)GRIDN);
  c = (c < 0) ? 0 : c;
  c = (c > GRIDN - 1) ? GRIDN - 1 : c;
  return c;
}

// ---------------------------------------------------------------------------
// K1: x = features @ W1.T + b1     [ROWS,32] x [64,32]^T -> [ROWS,64]
// ---------------------------------------------------------------------------
__global__ __launch_bounds__(256) void fc1_kernel(
    const float* __restrict__ f, const float* __restrict__ W1,
    const float* __restrict__ b1, float* __restrict__ x) {
  int gid = blockIdx.x * 256 + threadIdx.x;
  int n = gid >> 6, c = gid & 63;
  const float* fr = f + (size_t)n * DPT;
  const float* wr = W1 + c * DPT;
  float acc = b1[c];
#pragma unroll
  for (int i = 0; i < DPT; ++i) acc = fmaf(fr[i], wr[i], acc);
  x[(size_t)n * DM + c] = acc;
}

// ---------------------------------------------------------------------------
// K2a: build per-batch uniform grid over [0,1]^3.
// ---------------------------------------------------------------------------
__global__ __launch_bounds__(256) void grid_build_kernel(
    const float* __restrict__ xyz, int* __restrict__ cellStart,
    int* __restrict__ sortedIdx) {
  __shared__ int cnt[NCELL];     // 16 KB
  __shared__ int partial[256];
  int b = blockIdx.x, tid = threadIdx.x;
  const float* P = xyz + (size_t)b * NPTS * 3;

  for (int i = tid; i < NCELL; i += 256) cnt[i] = 0;
  __syncthreads();
  for (int i = tid; i < NPTS; i += 256) {
    int cx = cell_coord(P[3 * i + 0]);
    int cy = cell_coord(P[3 * i + 1]);
    int cz = cell_coord(P[3 * i + 2]);
    atomicAdd(&cnt[(cx << 8) | (cy << 4) | cz], 1);
  }
  __syncthreads();
  int base = tid * 16, s = 0;
#pragma unroll
  for (int j = 0; j < 16; ++j) s += cnt[base + j];
  partial[tid] = s;
  __syncthreads();
  if (tid == 0) {
    int acc = 0;
    for (int i = 0; i < 256; ++i) { int v = partial[i]; partial[i] = acc; acc += v; }
  }
  __syncthreads();
  int acc = partial[tid];
#pragma unroll
  for (int j = 0; j < 16; ++j) {
    int c = cnt[base + j];
    cnt[base + j] = acc;                          // becomes scatter cursor
    cellStart[b * (NCELL + 1) + base + j] = acc;  // exclusive start
    acc += c;
  }
  if (tid == 255) cellStart[b * (NCELL + 1) + NCELL] = NPTS;
  __syncthreads();
  for (int i = tid; i < NPTS; i += 256) {
    int cx = cell_coord(P[3 * i + 0]);
    int cy = cell_coord(P[3 * i + 1]);
    int cz = cell_coord(P[3 * i + 2]);
    int pos = atomicAdd(&cnt[(cx << 8) | (cy << 4) | cz], 1);
    sortedIdx[b * NPTS + pos] = i;
  }
}

// ---------------------------------------------------------------------------
// K2b: exact KNN via expanding cell shells + per-cell ball pruning.
// Distance metric IDENTICAL to the verified full-scan kernel.
// ---------------------------------------------------------------------------
__global__ __launch_bounds__(64) void grid_knn_kernel(
    const float* __restrict__ xyz, const int* __restrict__ cellStart,
    const int* __restrict__ sortedIdx, int* __restrict__ knn) {
  int t = blockIdx.x * 64 + threadIdx.x;   // 0..32767 sorted position
  int b = t >> 13, j = t & 8191;
  const int* cs = cellStart + b * (NCELL + 1);
  const int* si = sortedIdx + b * NPTS;
  const float* P = xyz + (size_t)b * NPTS * 3;

  int q = si[j];                // local point index (query)
  int n = (b << 13) + q;        // global row
  float qx = P[3 * q + 0], qy = P[3 * q + 1], qz = P[3 * q + 2];
  int cx = cell_coord(qx), cy = cell_coord(qy), cz = cell_coord(qz);

  unsigned long long key[KNN];
#pragma unroll
  for (int o = 0; o < KNN; ++o) key[o] = 0x7F800000FFFFFFFFULL;
  float lim = __builtin_inff();

  for (int rho = 0; rho <= GRIDN - 1; ++rho) {
    for (int dz = -rho; dz <= rho; ++dz) {
      int iz = cz + dz;
      if ((unsigned)iz >= GRIDN) continue;
      bool zface = (dz == -rho) || (dz == rho);
      for (int dy = -rho; dy <= rho; ++dy) {
        int iy = cy + dy;
        if ((unsigned)iy >= GRIDN) continue;
        bool face = zface || (dy == -rho) || (dy == rho);
        int dxstep = (rho == 0 || face) ? 1 : (2 * rho);
        for (int dx = -rho; dx <= rho; dx += dxstep) {
          int ix = cx + dx;
          if ((unsigned)ix >= GRIDN) continue;
          float bx = ix * CH, by = iy * CH, bz = iz * CH;
          float ex = fmaxf(fmaxf(bx - qx, qx - (bx + CH)), 0.f);
          float ey = fmaxf(fmaxf(by - qy, qy - (by + CH)), 0.f);
          float ez = fmaxf(fmaxf(bz - qz, qz - (bz + CH)), 0.f);
          float dsq = ex * ex + ey * ey + ez * ez;
          if (dsq * 0.99999f >= lim) continue;   // cannot beat current 24th
          int cid = (ix << 8) | (iy << 4) | iz;
          int s0 = cs[cid], s1 = cs[cid + 1];
          for (int ii = s0; ii < s1; ++ii) {
            int m = si[ii];
            float ddx = qx - P[3 * m + 0];
            float ddy = qy - P[3 * m + 1];
            float ddz = qz - P[3 * m + 2];
            double dd = (double)ddx * (double)ddx + (double)ddy * (double)ddy
                      + (double)ddz * (double)ddz;
            float df = (float)dd;
            if (df < lim) {
              unsigned long long v =
                  ((unsigned long long)__float_as_uint(df) << 32) | (unsigned)m;
#pragma unroll
              for (int tt = 0; tt < KNN; ++tt) {
                bool take = v < key[tt];
                unsigned long long old = key[tt];
                key[tt] = take ? v : key[tt];
                v = take ? old : v;
              }
              lim = __uint_as_float((unsigned)(key[KNN - 1] >> 32));
            }
          }
        }
      }
    }
    float rb = rho * CH;
    if (lim < rb * rb * 0.999999f) break;
  }
#pragma unroll
  for (int o = 0; o < KNN; ++o)
    knn[(size_t)n * KNN + o] = (int)(unsigned)key[o];
}

// ---------------------------------------------------------------------------
__device__ __forceinline__ float pe_elem(int t, float gx, float gy, float gz) {
  const float OM[10] = {1.0f, 0.3981071705534972f, 0.15848931924611134f,
                        0.06309573444801933f, 0.025118864315095794f, 0.01f,
                        0.003981071705534973f, 0.001584893192461114f,
                        0.0006309573444801933f, 0.00025118864315095795f};
  int a = t / 20, r = t % 20;
  float g = (a == 0) ? gx : ((a == 1) ? gy : gz);
  float ang = g * OM[r % 10];
  return (r < 10) ? __sinf(ang) : __cosf(ang);
}

// ---------------------------------------------------------------------------
// Shared MFMA MLP machinery (per-wave, one query per wave).
// scr: PE bf16 [32][64] swizzled -> H bf16 swizzled -> P bf16 [32][68] linear.
// ---------------------------------------------------------------------------
static __device__ __forceinline__ void pe_fill(
    unsigned short* scr, const float* __restrict__ xyz, const int* idxArr,
    int base, float qx, float qy, float qz, int ln) {
  for (int k = 0; k < KNN; ++k) {
    int gidx = base + idxArr[k];
    float gx = qx - xyz[(size_t)gidx * 3 + 0];
    float gy = qy - xyz[(size_t)gidx * 3 + 1];
    float gz = qz - xyz[(size_t)gidx * 3 + 2];
    float v = (ln < PED) ? pe_elem(ln, gx, gy, gz) : 0.f;
    scr[(k * 64 + ln) ^ ((k & 7) << 3)] = f2bf(v);
  }
#pragma unroll
  for (int k = KNN; k < 32; ++k)
    scr[(k * 64 + ln) ^ ((k & 7) << 3)] = 0;
  WSYNC();
}

static __device__ __forceinline__ short8 lds_read8(const unsigned short* p) {
  return *(const short8*)p;
}

static __device__ __forceinline__ void mlp_wave(
    unsigned short* scr, const unsigned short* w1b, const unsigned short* w2b,
    const float* __restrict__ bd1, const float* __restrict__ bd2, int ln) {
  int lrow = ln & 15, lq = ln >> 4;
  short8 af[2][2], bfr[4][2];
  f32x4 acc[2][4];

  // ---- layer 1: H = relu(PE @ Wd1^T + bd1)
#pragma unroll
  for (int mt = 0; mt < 2; ++mt)
#pragma unroll
    for (int ks = 0; ks < 2; ++ks) {
      int row = mt * 16 + lrow;
      af[mt][ks] = lds_read8(scr + ((row * 64 + ks * 32 + lq * 8) ^ ((row & 7) << 3)));
    }
#pragma unroll
  for (int nt = 0; nt < 4; ++nt)
#pragma unroll
    for (int ks = 0; ks < 2; ++ks) {
      int row = nt * 16 + lrow;
      bfr[nt][ks] = lds_read8(w1b + ((row * 64 + ks * 32 + lq * 8) ^ ((row & 7) << 3)));
    }
#pragma unroll
  for (int mt = 0; mt < 2; ++mt)
#pragma unroll
    for (int nt = 0; nt < 4; ++nt) {
      f32x4 a = (f32x4){0.f, 0.f, 0.f, 0.f};
      a = __builtin_amdgcn_mfma_f32_16x16x32_bf16(af[mt][0], bfr[nt][0], a, 0, 0, 0);
      a = __builtin_amdgcn_mfma_f32_16x16x32_bf16(af[mt][1], bfr[nt][1], a, 0, 0, 0);
      acc[mt][nt] = a;
    }
  WSYNC();
#pragma unroll
  for (int mt = 0; mt < 2; ++mt)
#pragma unroll
    for (int nt = 0; nt < 4; ++nt) {
      float b1v = bd1[nt * 16 + lrow];
#pragma unroll
      for (int r = 0; r < 4; ++r) {
        int row = mt * 16 + lq * 4 + r;
        int col = nt * 16 + lrow;
        scr[(row * 64 + col) ^ ((row & 7) << 3)] =
            f2bf(fmaxf(acc[mt][nt][r] + b1v, 0.f));
      }
    }
  WSYNC();
  // ---- layer 2: P = H @ Wd2^T + bd2
#pragma unroll
  for (int mt = 0; mt < 2; ++mt)
#pragma unroll
    for (int ks = 0; ks < 2; ++ks) {
      int row = mt * 16 + lrow;
      af[mt][ks] = lds_read8(scr + ((row * 64 + ks * 32 + lq * 8) ^ ((row & 7) << 3)));
    }
#pragma unroll
  for (int nt = 0; nt < 4; ++nt)
#pragma unroll
    for (int ks = 0; ks < 2; ++ks) {
      int row = nt * 16 + lrow;
      bfr[nt][ks] = lds_read8(w2b + ((row * 64 + ks * 32 + lq * 8) ^ ((row & 7) << 3)));
    }
#pragma unroll
  for (int mt = 0; mt < 2; ++mt)
#pragma unroll
    for (int nt = 0; nt < 4; ++nt) {
      f32x4 a = (f32x4){0.f, 0.f, 0.f, 0.f};
      a = __builtin_amdgcn_mfma_f32_16x16x32_bf16(af[mt][0], bfr[nt][0], a, 0, 0, 0);
      a = __builtin_amdgcn_mfma_f32_16x16x32_bf16(af[mt][1], bfr[nt][1], a, 0, 0, 0);
      acc[mt][nt] = a;
    }
  WSYNC();
#pragma unroll
  for (int mt = 0; mt < 2; ++mt)
#pragma unroll
    for (int nt = 0; nt < 4; ++nt) {
      float b2v = bd2[nt * 16 + lrow];
#pragma unroll
      for (int r = 0; r < 4; ++r) {
        int row = mt * 16 + lq * 4 + r;
        int col = nt * 16 + lrow;
        scr[row * 68 + col] = f2bf(acc[mt][nt][r] + b2v);
      }
    }
  WSYNC();
}

// ---------------------------------------------------------------------------
// K3: pre[n] = bf16(q - kf + pos_enc) -> preOut (packed [ROWS][1536]).
// If P16 != null, also store P bf16 into attn-row upper halves:
//   P16 + n*3072 + 1536 + k*64 + ln    (attn row n byte 6144n+3072).
// ---------------------------------------------------------------------------
__global__ __launch_bounds__(256) void prebuild_kernel(
    const float* __restrict__ xyz, const float* __restrict__ x,
    const int* __restrict__ knn,
    const float* __restrict__ Wd1, const float* __restrict__ bd1,
    const float* __restrict__ Wd2, const float* __restrict__ bd2,
    unsigned short* __restrict__ preOut, unsigned short* __restrict__ P16) {
  __shared__ unsigned short sW1b[4096];
  __shared__ unsigned short sW2bb[4096];
  __shared__ unsigned short sScr[4][2176];
  __shared__ int sIdx[4][KNN];
  int tid = threadIdx.x, w = tid >> 6, ln = tid & 63;
  int n = blockIdx.x * 4 + w, b = n >> 13;

  for (int q = tid; q < 4096; q += 256) {
    int row = q >> 6, kk = q & 63;
    int idx = q ^ ((row & 7) << 3);
    sW1b[idx] = (kk < PED) ? f2bf(Wd1[row * PED + kk]) : (unsigned short)0;
    sW2bb[idx] = f2bf(Wd2[q]);
  }
  if (ln < KNN) sIdx[w][ln] = knn[(size_t)n * KNN + ln];
  __syncthreads();

  float qx = xyz[(size_t)n * 3], qy = xyz[(size_t)n * 3 + 1], qz = xyz[(size_t)n * 3 + 2];
  float xq = x[(size_t)n * DM + ln];
  unsigned short* scr = &sScr[w][0];

  pe_fill(scr, xyz, &sIdx[w][0], b << 13, qx, qy, qz, ln);
  mlp_wave(scr, sW1b, sW2bb, bd1, bd2, ln);

  for (int k = 0; k < KNN; ++k) {
    int gidx = (b << 13) + sIdx[w][k];
    float kfv = x[(size_t)gidx * DM + ln];
    float p = bf2f(scr[k * 68 + ln]);
    preOut[((size_t)n * KNN + k) * DM + ln] = f2bf(xq - kfv + p);
  }
  if (P16) {
    unsigned short* pd = P16 + (size_t)n * 3072 + 1536;
#pragma unroll
    for (int k = 0; k < KNN; ++k) pd[k * 64 + ln] = scr[k * 68 + ln];
  }
}

// ---------------------------------------------------------------------------
// K4a: f32 -> bf16 convert (vectorized) — Wa only.
// ---------------------------------------------------------------------------
__global__ __launch_bounds__(256) void conv_bf16_kernel(
    const float* __restrict__ src, unsigned short* __restrict__ dst, int n4) {
  int i = blockIdx.x * 256 + threadIdx.x;
  if (i < n4) {
    float4 v = ((const float4*)src)[i];
    ushort4 o;
    o.x = f2bf(v.x); o.y = f2bf(v.y); o.z = f2bf(v.z); o.w = f2bf(v.w);
    ((ushort4*)dst)[i] = o;
  }
}

// 16B copy kernel (fallback path only)
__global__ __launch_bounds__(256) void copy16_kernel(
    const uint4* __restrict__ src, uint4* __restrict__ dst, int nvec) {
  int i = blockIdx.x * 256 + threadIdx.x;
  if (i < nvec) dst[i] = src[i];
}

// ---------------------------------------------------------------------------
// K4b: logits(bf16) = pre_bf16 @ Wa_bf16.T + ba. 128x128 tiles, 12 n-tiles.
// 1-D grid; bijective XCD-chunked swizzle so the 12 n-tiles sharing an
// A-panel land contiguously on one XCD (A fetched ~once per L2).
// C is bf16, row pitch 3072 ushorts (attn row n lower half).
// ---------------------------------------------------------------------------
__global__ __launch_bounds__(256) void gemm_bf16_kernel(
    const unsigned short* __restrict__ A,   // [cr][1536] bf16 packed
    const unsigned short* __restrict__ B,   // Wa bf16 [1536][1536]
    const float* __restrict__ ba,
    unsigned short* __restrict__ Cb) {      // bf16, row pitch 3072 ushorts
  __shared__ unsigned short sA[8 * 512];
  __shared__ unsigned short sB[8 * 512];
  unsigned nwg = gridDim.x, orig = blockIdx.x;
  unsigned xcd = orig & 7u, qd = nwg >> 3, rr = nwg & 7u;
  unsigned wgid = (xcd < rr ? xcd * (qd + 1) : rr * (qd + 1) + (xcd - rr) * qd)
                + (orig >> 3);
  int mt = wgid / 12, nt = wgid % 12;
  int m0 = mt * 128, n0 = nt * 128;
  int tid = threadIdx.x, w = tid >> 6, L = tid & 63;
  int wr = w >> 1, wc = w & 1;
  int lrow = L & 15, lq = L >> 4;

  f32x4 acc[4][4];
#pragma unroll
  for (int i = 0; i < 4; ++i)
#pragma unroll
    for (int j = 0; j < 4; ++j) acc[i][j] = (f32x4){0.f, 0.f, 0.f, 0.f};

  for (int kt = 0; kt < DK; kt += 32) {
#pragma unroll
    for (int i = 0; i < 2; ++i) {
      int tb = w * 2 + i;
      const unsigned short* ga = A + ((size_t)(m0 + tb * 16 + lrow)) * DK + kt + lq * 8;
      __builtin_amdgcn_global_load_lds((gbl_u32*)ga, (lds_u32*)(sA + tb * 512), 16, 0, 0);
      const unsigned short* gb = B + ((size_t)(n0 + tb * 16 + lrow)) * DK + kt + lq * 8;
      __builtin_amdgcn_global_load_lds((gbl_u32*)gb, (lds_u32*)(sB + tb * 512), 16, 0, 0);
    }
    __syncthreads();
    short8 af[4], bf[4];
#pragma unroll
    for (int i = 0; i < 4; ++i)
      af[i] = *(const short8*)(sA + ((wr * 4 + i) * 64 + L) * 8);
#pragma unroll
    for (int j = 0; j < 4; ++j)
      bf[j] = *(const short8*)(sB + ((wc * 4 + j) * 64 + L) * 8);
#pragma unroll
    for (int i = 0; i < 4; ++i)
#pragma unroll
      for (int j = 0; j < 4; ++j)
        acc[i][j] = __builtin_amdgcn_mfma_f32_16x16x32_bf16(af[i], bf[j], acc[i][j], 0, 0, 0);
    __syncthreads();
  }
#pragma unroll
  for (int j = 0; j < 4; ++j) {
    int col = n0 + (wc * 4 + j) * 16 + lrow;
    float bav = ba[col];
#pragma unroll
    for (int i = 0; i < 4; ++i) {
      int rbase = m0 + (wr * 4 + i) * 16 + lq * 4;
#pragma unroll
      for (int r = 0; r < 4; ++r)
        Cb[(size_t)(rbase + r) * 3072 + col] = f2bf(acc[i][j][r] + bav);
    }
  }
}

// ---------------------------------------------------------------------------
// K5-lean (big-ws): softmax over K from bf16 logits (attn-row lower half),
// P from upper half; einsum + fc2 + residual; write f32 attn over the row.
// attn16/attnF alias by design -> NOT restrict; reads precede writes.
// ---------------------------------------------------------------------------
__global__ __launch_bounds__(256) void finish_kernel(
    const float* __restrict__ x, const int* __restrict__ knn,
    const float* __restrict__ W2, const float* __restrict__ b2,
    const unsigned short* attn16, float* attnF, float* __restrict__ res) {
  __shared__ float sW2f[DM][DM + 1];
  __shared__ float sRes[4][64];
  __shared__ int sIdx[4][KNN];
  int tid = threadIdx.x, w = tid >> 6, ln = tid & 63;
  int n = blockIdx.x * 4 + w, b = n >> 13;

  for (int q = tid; q < DM * DM; q += 256) sW2f[q >> 6][q & 63] = W2[q];
  if (ln < KNN) sIdx[w][ln] = knn[(size_t)n * KNN + ln];
  __syncthreads();

  const unsigned short* lrow = attn16 + (size_t)n * 3072;
  float L[KNN], Pv[KNN];
#pragma unroll
  for (int k = 0; k < KNN; ++k) L[k] = bf2f(lrow[k * 64 + ln]);
#pragma unroll
  for (int k = 0; k < KNN; ++k) Pv[k] = bf2f(lrow[1536 + k * 64 + ln]);
  asm volatile("" ::: "memory");   // all reads of row n before any write

  float mx = -__builtin_inff();
#pragma unroll
  for (int k = 0; k < KNN; ++k) mx = fmaxf(mx, L[k]);
  float ssum = 0.f;
#pragma unroll
  for (int k = 0; k < KNN; ++k) { L[k] = __expf((L[k] - mx) * 0.125f); ssum += L[k]; }
  float inv = 1.0f / ssum;
#pragma unroll
  for (int k = 0; k < KNN; ++k) {
    L[k] *= inv;
    attnF[(size_t)n * DK + k * 64 + ln] = L[k];
  }

  float racc = 0.f;
  for (int k = 0; k < KNN; ++k) {
    int gidx = (b << 13) + sIdx[w][k];
    float xv = x[(size_t)gidx * DM + ln];
    racc = fmaf(L[k], xv + Pv[k], racc);
  }
  sRes[w][ln] = racc;
  WSYNC();
  float oacc = b2[ln] + x[(size_t)n * DM + ln];
#pragma unroll
  for (int o = 0; o < DM; ++o) oacc = fmaf(sRes[w][o], sW2f[ln][o], oacc);
  res[(size_t)n * DM + ln] = oacc;
}

// ---------------------------------------------------------------------------
// K5-full (small-ws fallback): recompute MLP via MFMA, bf16 logits in.
// ---------------------------------------------------------------------------
__global__ __launch_bounds__(256) void finish_full_kernel(
    const float* __restrict__ xyz, const float* __restrict__ x,
    const int* __restrict__ knn,
    const float* __restrict__ Wd1, const float* __restrict__ bd1,
    const float* __restrict__ Wd2, const float* __restrict__ bd2,
    const float* __restrict__ W2, const float* __restrict__ b2,
    const unsigned short* attn16, float* attnF, float* __restrict__ res) {
  __shared__ unsigned short sW1b[4096];
  __shared__ unsigned short sW2bb[4096];
  __shared__ float sW2f[DM][DM + 1];
  __shared__ unsigned short sScr[4][2176];
  __shared__ float sRes[4][64];
  __shared__ int sIdx[4][KNN];
  int tid = threadIdx.x, w = tid >> 6, ln = tid & 63;
  int n = blockIdx.x * 4 + w, b = n >> 13;

  for (int q = tid; q < 4096; q += 256) {
    int row = q >> 6, kk = q & 63;
    int idx = q ^ ((row & 7) << 3);
    sW1b[idx] = (kk < PED) ? f2bf(Wd1[row * PED + kk]) : (unsigned short)0;
    sW2bb[idx] = f2bf(Wd2[q]);
  }
  for (int q = tid; q < DM * DM; q += 256) sW2f[q >> 6][q & 63] = W2[q];
  if (ln < KNN) sIdx[w][ln] = knn[(size_t)n * KNN + ln];
  __syncthreads();

  float qx = xyz[(size_t)n * 3], qy = xyz[(size_t)n * 3 + 1], qz = xyz[(size_t)n * 3 + 2];
  unsigned short* scr = &sScr[w][0];
  pe_fill(scr, xyz, &sIdx[w][0], b << 13, qx, qy, qz, ln);
  mlp_wave(scr, sW1b, sW2bb, bd1, bd2, ln);

  const unsigned short* lrow = attn16 + (size_t)n * 3072;
  float L[KNN];
#pragma unroll
  for (int k = 0; k < KNN; ++k) L[k] = bf2f(lrow[k * 64 + ln]);
  asm volatile("" ::: "memory");
  float mx = -__builtin_inff();
#pragma unroll
  for (int k = 0; k < KNN; ++k) mx = fmaxf(mx, L[k]);
  float ssum = 0.f;
#pragma unroll
  for (int k = 0; k < KNN; ++k) { L[k] = __expf((L[k] - mx) * 0.125f); ssum += L[k]; }
  float inv = 1.0f / ssum;
#pragma unroll
  for (int k = 0; k < KNN; ++k) {
    L[k] *= inv;
    attnF[(size_t)n * DK + k * 64 + ln] = L[k];
  }
  float racc = 0.f;
  for (int k = 0; k < KNN; ++k) {
    int gidx = (b << 13) + sIdx[w][k];
    float xv = x[(size_t)gidx * DM + ln];
    racc = fmaf(L[k], xv + bf2f(scr[k * 68 + ln]), racc);
  }
  sRes[w][ln] = racc;
  WSYNC();
  float oacc = b2[ln] + x[(size_t)n * DM + ln];
#pragma unroll
  for (int o = 0; o < DM; ++o) oacc = fmaf(sRes[w][o], sW2f[ln][o], oacc);
  res[(size_t)n * DM + ln] = oacc;
}

// ---------------------------------------------------------------------------
extern "C" void kernel_launch(void* const* d_in, const int* in_sizes, int n_in,
                              void* d_out, int out_size, void* d_ws, size_t ws_size,
                              hipStream_t stream) {
  const float* features = (const float*)d_in[0];
  const float* xyz = (const float*)d_in[1];
  const float* W1  = (const float*)d_in[2];
  const float* b1  = (const float*)d_in[3];
  const float* W2  = (const float*)d_in[4];
  const float* b2  = (const float*)d_in[5];
  const float* Wd1 = (const float*)d_in[6];
  const float* bd1 = (const float*)d_in[7];
  const float* Wd2 = (const float*)d_in[8];
  const float* bd2 = (const float*)d_in[9];
  const float* Wa  = (const float*)d_in[10];
  const float* ba  = (const float*)d_in[11];

  float* res  = (float*)d_out;                      // [ROWS*64]
  float* attn = (float*)d_out + (size_t)ROWS * DM;  // [ROWS*1536] f32 region
  unsigned short* attn16 = (unsigned short*)attn;   // bf16 view (pitch 3072/row)

  size_t xB   = (size_t)ROWS * DM * 4;              // 8,388,608
  size_t WaB  = (size_t)DK * DK * 2;                // 4,718,592
  size_t used = xB + (size_t)ROWS * KNN * 4;
  float* xbuf = (float*)d_ws;
  int*   knn  = (int*)((char*)d_ws + xB);

  size_t avail = (ws_size > used) ? ws_size - used : 0;
  size_t rowB = (size_t)DK * 2;                     // bf16 row = 3072 B
  bool bigws = avail >= WaB + (size_t)ROWS * rowB;  // 105.4 MB

  // Grid scratch at attn head; consumed by grid_knn before prebuild writes.
  int* gridCS = (int*)attn;
  int* gridSI = gridCS + BATCH * (NCELL + 1);

  hipLaunchKernelGGL(fc1_kernel, dim3(ROWS * DM / 256), dim3(256), 0, stream,
                     features, W1, b1, xbuf);
  hipLaunchKernelGGL(grid_build_kernel, dim3(BATCH), dim3(256), 0, stream,
                     xyz, gridCS, gridSI);
  hipLaunchKernelGGL(grid_knn_kernel, dim3(ROWS / 64), dim3(64), 0, stream,
                     xyz, gridCS, gridSI, knn);

  if (bigws) {
    unsigned short* WaBf = (unsigned short*)((char*)d_ws + used);
    unsigned short* preW = (unsigned short*)((char*)d_ws + used + WaB); // 100.7MB
    // prebuild: pre -> ws (packed); P bf16 -> attn-row upper halves
    hipLaunchKernelGGL(prebuild_kernel, dim3(ROWS / 4), dim3(256), 0, stream,
                       xyz, xbuf, knn, Wd1, bd1, Wd2, bd2, preW, attn16);
    {
      int n4 = DK * DK / 4;
      hipLaunchKernelGGL(conv_bf16_kernel, dim3((n4 + 255) / 256), dim3(256), 0, stream,
                         Wa, WaBf, n4);
    }
    // single GEMM: A=ws pre, C bf16 -> attn-row lower halves (no hazard)
    hipLaunchKernelGGL(gemm_bf16_kernel, dim3((ROWS / 128) * 12), dim3(256), 0, stream,
                       preW, WaBf, ba, attn16);
    hipLaunchKernelGGL(finish_kernel, dim3(ROWS / 4), dim3(256), 0, stream,
                       xbuf, knn, W2, b2, attn16, attn, res);
  } else {
    // Fallback: pre packed at attn front; WaBf+chunk scratch in res region.
    unsigned short* WaBf  = (unsigned short*)d_out;
    unsigned short* chunk = (unsigned short*)((char*)d_out + WaB);
    int chunk_rows = (int)((xB - WaB) / rowB) & ~127;   // 1152
    hipLaunchKernelGGL(prebuild_kernel, dim3(ROWS / 4), dim3(256), 0, stream,
                       xyz, xbuf, knn, Wd1, bd1, Wd2, bd2, attn16,
                       (unsigned short*)nullptr);
    {
      int n4 = DK * DK / 4;
      hipLaunchKernelGGL(conv_bf16_kernel, dim3((n4 + 255) / 256), dim3(256), 0, stream,
                         Wa, WaBf, n4);
    }
    {
      int cr0 = (chunk_rows < ROWS) ? chunk_rows : ROWS;
      int nvec = cr0 * (DK * 2 / 16);
      hipLaunchKernelGGL(copy16_kernel, dim3((nvec + 255) / 256), dim3(256), 0, stream,
                         (const uint4*)attn16, (uint4*)chunk, nvec);
    }
    // Descending chunks: bf16 logits row n (3072B at byte 6144n) clobbers
    // packed pre row 2n only; later (lower) chunks read rows < r0 <= 2*r0.
    int top = ((ROWS - 1) / chunk_rows) * chunk_rows;
    for (int r0 = top; r0 >= 0; r0 -= chunk_rows) {
      int cr = (ROWS - r0 < chunk_rows) ? (ROWS - r0) : chunk_rows;
      const unsigned short* Aptr =
          (r0 == 0) ? chunk : attn16 + (size_t)r0 * DK;
      hipLaunchKernelGGL(gemm_bf16_kernel, dim3((cr / 128) * 12), dim3(256), 0, stream,
                         Aptr, WaBf, ba, attn16 + (size_t)r0 * 3072);
    }
    hipLaunchKernelGGL(finish_full_kernel, dim3(ROWS / 4), dim3(256), 0, stream,
                       xyz, xbuf, knn, Wd1, bd1, Wd2, bd2, W2, b2,
                       attn16, attn, res);
  }
}